// Round 10
// baseline (171.643 us; speedup 1.0000x reference)
//
#include <hip/hip_runtime.h>
#include <hip/hip_bf16.h>
#include <stdint.h>

typedef unsigned short u16;
typedef unsigned int   u32;
typedef unsigned long long u64;

typedef __attribute__((ext_vector_type(8)))  short short8;   // 8 bf16 (4 VGPR)
typedef __attribute__((ext_vector_type(4)))  u32   u32x4;
typedef __attribute__((ext_vector_type(4)))  float f32x4;
typedef __attribute__((ext_vector_type(16))) float f32x16;

// ---- helpers -------------------------------------------------------------

__device__ __forceinline__ u16 f2bf(float f) {           // RNE f32 -> bf16 bits
  u32 u = __builtin_bit_cast(u32, f);
  u += 0x7FFFu + ((u >> 16) & 1u);
  return (u16)(u >> 16);
}

__device__ __forceinline__ void gload16(const void* g, void* l) {
  __builtin_amdgcn_global_load_lds((__attribute__((address_space(1))) void*)(g),
                                   (__attribute__((address_space(3))) void*)(l),
                                   16, 0, 0);
}

__device__ __forceinline__ u32 cvtpk(float lo, float hi) {
  u32 r;
  asm("v_cvt_pk_bf16_f32 %0, %1, %2" : "=v"(r) : "v"(lo), "v"(hi));
  return r;
}

// ---- fused f32 -> bf16 converts ------------------------------------------

__global__ __launch_bounds__(256)
void cvt3_kernel(const float* __restrict__ a, const float* __restrict__ b,
                 const float* __restrict__ c, u16* __restrict__ oa,
                 u16* __restrict__ ob, u16* __restrict__ oc, int n4) {
  int i = blockIdx.x * 256 + threadIdx.x;
  if (i >= n4) return;
  const float* in = blockIdx.y == 0 ? a : blockIdx.y == 1 ? b : c;
  u16* out = blockIdx.y == 0 ? oa : blockIdx.y == 1 ? ob : oc;
  float4 v = reinterpret_cast<const float4*>(in)[i];
  u64 pk = (u64)f2bf(v.x) | ((u64)f2bf(v.y) << 16)
         | ((u64)f2bf(v.z) << 32) | ((u64)f2bf(v.w) << 48);
  reinterpret_cast<u64*>(out)[i] = pk;
}

__global__ __launch_bounds__(256)
void cvtw_kernel(const float* __restrict__ Wq, const float* __restrict__ Wk,
                 const float* __restrict__ Wv, const float* __restrict__ Wo,
                 u16* __restrict__ Wcat, u16* __restrict__ WoB, int n4, float qs) {
  int i = blockIdx.x * 256 + threadIdx.x;
  if (i >= n4) return;
  int y = blockIdx.y;
  const float* in = y == 0 ? Wq : y == 1 ? Wk : y == 2 ? Wv : Wo;
  u16* out = y == 0 ? Wcat : y == 1 ? (Wcat + 589824) : y == 2 ? (Wcat + 1179648) : WoB;
  float s = y == 0 ? qs : 1.f;
  float4 v = reinterpret_cast<const float4*>(in)[i];
  u64 pk = (u64)f2bf(v.x * s) | ((u64)f2bf(v.y * s) << 16)
         | ((u64)f2bf(v.z * s) << 32) | ((u64)f2bf(v.w * s) << 48);
  reinterpret_cast<u64*>(out)[i] = pk;
}

// ---- 128x128 tile GEMM, C = A @ B^T (nn.Linear), bf16 MFMA ---------------
// 1D grid + bijective XCD swizzle, decoded bn-fastest.
template<int MODE>
__global__ __launch_bounds__(256)
void gemm128(const u16* __restrict__ Aq, const u16* __restrict__ Ak,
             const u16* __restrict__ Av, const u16* __restrict__ Bw,
             u16* __restrict__ Cqk, u16* __restrict__ Vt,
             float* __restrict__ Cout, const float* __restrict__ bias) {
  constexpr int K  = 768;
  constexpr int KT = K / 32;
  constexpr int NBN = (MODE == 0) ? 18 : 6;
  __shared__ char lds[32768];
  char* A0 = lds;          char* A1 = lds + 8192;
  char* B0 = lds + 16384;  char* B1 = lds + 24576;

  const int tid = threadIdx.x, lane = tid & 63, wid = tid >> 6;
  const int hw = blockIdx.x;
  const int L = (hw & 7) * (64 * NBN / 8) + (hw >> 3);
  const int bm = L / NBN, bn = L - bm * NBN;
  const int wr = wid >> 1, wc = wid & 1;

  const u16* Abase = Aq;
  if constexpr (MODE == 0) Abase = (bn < 6) ? Aq : (bn < 12) ? Ak : Av;

  const char* Ag = (const char*)Abase + (size_t)bm * 128 * (K * 2);
  const char* Bg = (const char*)Bw    + (size_t)bn * 128 * (K * 2);

  f32x4 acc[4][4];
  #pragma unroll
  for (int m = 0; m < 4; ++m)
    #pragma unroll
    for (int n = 0; n < 4; ++n)
      #pragma unroll
      for (int r = 0; r < 4; ++r) acc[m][n][r] = 0.f;

  #pragma unroll
  for (int c = 0; c < 2; ++c) {
    int chunk = c * 4 + wid;
    int off = chunk * 1024 + lane * 16;
    int row = off >> 6, colb = off & 63;
    gload16(Ag + (size_t)row * (K * 2) + colb, A0 + chunk * 1024);
    gload16(Bg + (size_t)row * (K * 2) + colb, B0 + chunk * 1024);
  }
  __syncthreads();

  for (int kt = 0; kt < KT; ++kt) {
    const int cur = kt & 1;
    char* Ac = cur ? A1 : A0;  char* Bc = cur ? B1 : B0;
    char* An = cur ? A0 : A1;  char* Bn = cur ? B0 : B1;
    if (kt + 1 < KT) {
      #pragma unroll
      for (int c = 0; c < 2; ++c) {
        int chunk = c * 4 + wid;
        int off = chunk * 1024 + lane * 16;
        int row = off >> 6, colb = off & 63;
        gload16(Ag + (size_t)row * (K * 2) + (kt + 1) * 64 + colb, An + chunk * 1024);
        gload16(Bg + (size_t)row * (K * 2) + (kt + 1) * 64 + colb, Bn + chunk * 1024);
      }
    }
    short8 af[4], bf[4];
    #pragma unroll
    for (int m = 0; m < 4; ++m) {
      int row = wr * 64 + m * 16 + (lane & 15);
      af[m] = *reinterpret_cast<const short8*>(Ac + row * 64 + ((lane >> 4) * 16));
    }
    #pragma unroll
    for (int n = 0; n < 4; ++n) {
      int row = wc * 64 + n * 16 + (lane & 15);
      bf[n] = *reinterpret_cast<const short8*>(Bc + row * 64 + ((lane >> 4) * 16));
    }
    #pragma unroll
    for (int m = 0; m < 4; ++m)
      #pragma unroll
      for (int n = 0; n < 4; ++n)
        acc[m][n] = __builtin_amdgcn_mfma_f32_16x16x32_bf16(af[m], bf[n], acc[m][n], 0, 0, 0);
    __syncthreads();
  }

  if constexpr (MODE == 0) {
    if (bn < 12) {
      #pragma unroll
      for (int m = 0; m < 4; ++m) {
        int grow0 = bm * 128 + wr * 64 + m * 16 + ((lane >> 4) << 2);
        #pragma unroll
        for (int n = 0; n < 4; ++n) {
          int col = bn * 128 + wc * 64 + n * 16 + (lane & 15);
          #pragma unroll
          for (int r = 0; r < 4; ++r)
            Cqk[(size_t)(grow0 + r) * 1536 + col] = f2bf(acc[m][n][r]);
        }
      }
    } else {
      #pragma unroll
      for (int m = 0; m < 4; ++m) {
        int grow0 = bm * 128 + wr * 64 + m * 16 + ((lane >> 4) << 2);
        int bb = grow0 >> 11, nn = grow0 & 2047;
        #pragma unroll
        for (int n = 0; n < 4; ++n) {
          int vc = (bn - 12) * 128 + wc * 64 + n * 16 + (lane & 15);
          int hid = vc >> 6, d = vc & 63;
          u64 pk = (u64)f2bf(acc[m][n][0]) | ((u64)f2bf(acc[m][n][1]) << 16)
                 | ((u64)f2bf(acc[m][n][2]) << 32) | ((u64)f2bf(acc[m][n][3]) << 48);
          *reinterpret_cast<u64*>(Vt + ((size_t)(bb * 12 + hid) * 64 + d) * 2048 + nn) = pk;
        }
      }
    }
  } else {
    #pragma unroll
    for (int m = 0; m < 4; ++m) {
      int grow0 = bm * 128 + wr * 64 + m * 16 + ((lane >> 4) << 2);
      #pragma unroll
      for (int n = 0; n < 4; ++n) {
        int col = bn * 128 + wc * 64 + n * 16 + (lane & 15);
        float bs = bias[col];
        #pragma unroll
        for (int r = 0; r < 4; ++r)
          Cout[(size_t)(grow0 + r) * 768 + col] = acc[m][n][r] + bs;
      }
    }
  }
}

// ---- flash attention, swapped-operand 32x32 MFMA -------------------------
// R9-passing body; single change: 2-DEEP staging pipeline (T3/T4-lite).
// Triple-buffered K/V; stage tile t+2 at tile t; end-of-tile uses counted
// s_waitcnt vmcnt(4) (waits only the PREVIOUS tile's batch) + raw s_barrier
// -- the vmcnt(0) drain of __syncthreads is gone from the main loop.
__global__ __launch_bounds__(256)
void attn_fwd(const u16* __restrict__ QK, const u16* __restrict__ Vt,
              u16* __restrict__ X) {
  __shared__ char lds[49152];
  char* Kb0 = lds;          char* Kb1 = lds + 8192;   char* Kb2 = lds + 16384;
  char* Vb0 = lds + 24576;  char* Vb1 = lds + 32768;  char* Vb2 = lds + 40960;

  const int tid = threadIdx.x, lane = tid & 63, wid = tid >> 6;
  // bijective XCD swizzle: grid 768 = 8 * 96
  const int hw = blockIdx.x;
  const int L = (hw & 7) * 96 + (hw >> 3);
  const int bh = L >> 4, qt = L & 15;
  const int b = bh / 12, h = bh - b * 12;
  const int hh = lane >> 5;

  const char* Qg = (const char*)QK + ((size_t)(b * 2048 + qt * 128) * 1536 + h * 64) * 2;
  const char* Kg = (const char*)QK + ((size_t)(b * 2048) * 1536 + 768 + h * 64) * 2;
  const char* Vg = (const char*)Vt + ((size_t)bh * 64 * 2048) * 2;

  // staging constants: 2 chunks (1KB each) per thread for K and for V
  const int off0 = wid * 1024 + lane * 16;
  const int off1 = off0 + 4096;
  const int r0 = off0 >> 7, i0 = (off0 & 127) ^ ((r0 & 7) << 4);
  const int r1 = off1 >> 7, i1 = (off1 & 127) ^ ((r1 & 7) << 4);
  // K source rows permuted: pi(r) = (r&32) | pblk(r>>2 & 7)<<2 | (r&3),
  // pblk = swap bits 0<->1  (bijective; applied only to K, not V)
  const int pb0 = (r0 >> 2) & 7, pb1 = (r1 >> 2) & 7;
  const int kr0 = (r0 & 32) | ((((pb0 & 1) << 1) | ((pb0 >> 1) & 1) | (pb0 & 4)) << 2) | (r0 & 3);
  const int kr1 = (r1 & 32) | ((((pb1 & 1) << 1) | ((pb1 >> 1) & 1) | (pb1 & 4)) << 2) | (r1 & 3);
  const size_t kso0 = (size_t)kr0 * 3072 + i0, kso1 = (size_t)kr1 * 3072 + i1;
  const size_t vso0 = (size_t)r0 * 4096 + i0, vso1 = (size_t)r1 * 4096 + i1;

  auto stage = [&](int t, char* Kd, char* Vd) {
    const char* Kgn = Kg + (size_t)t * 64 * 3072;
    const char* Vgn = Vg + (size_t)t * 128;
    gload16(Kgn + kso0, Kd + off0);
    gload16(Kgn + kso1, Kd + off1);
    gload16(Vgn + vso0, Vd + off0);
    gload16(Vgn + vso1, Vd + off1);
  };

  // prologue: stage t=0 and t=1 (2-deep)
  stage(0, Kb0, Vb0);
  stage(1, Kb1, Vb1);

  // Q fragments once, straight from global: q=lane&31, d = kk*16 + hh*8 + e
  short8 qf[4];
  {
    const char* Qrow = Qg + (size_t)(wid * 32 + (lane & 31)) * 3072 + hh * 16;
    #pragma unroll
    for (int kk = 0; kk < 4; ++kk)
      qf[kk] = *reinterpret_cast<const short8*>(Qrow + kk * 32);
  }
  asm volatile("s_waitcnt vmcnt(8)" ::: "memory");   // t=0 batch complete
  __builtin_amdgcn_s_barrier();

  f32x16 o0, o1;
  #pragma unroll
  for (int r = 0; r < 16; ++r) { o0[r] = 0.f; o1[r] = 0.f; }
  float l_run = 0.f;

  auto tile_body = [&](const char* Kc, const char* Vc) {
    // S^T: sa = kv 0..31 group, sb = kv 32..63 group (rows permuted by pi)
    f32x16 sa, sb;
    #pragma unroll
    for (int r = 0; r < 16; ++r) { sa[r] = 0.f; sb[r] = 0.f; }
    {
      const int ra = lane & 31;
      const int swa = (ra & 7) << 4;
      const char* Ka = Kc + ra * 128;
      const char* Kb_ = Kc + (32 + ra) * 128;   // (32+ra)&7 == ra&7
      __builtin_amdgcn_s_setprio(1);
      #pragma unroll
      for (int kk = 0; kk < 4; ++kk) {
        int inner = (kk * 32 + hh * 16) ^ swa;
        short8 ka = *reinterpret_cast<const short8*>(Ka + inner);
        short8 kb = *reinterpret_cast<const short8*>(Kb_ + inner);
        sa = __builtin_amdgcn_mfma_f32_32x32x16_bf16(ka, qf[kk], sa, 0, 0, 0);
        sb = __builtin_amdgcn_mfma_f32_32x32x16_bf16(kb, qf[kk], sb, 0, 0, 0);
      }
      __builtin_amdgcn_s_setprio(0);
    }

    // MAX-FREE: P = exp2(S); own-half partial sums (cross-half hoisted)
    float pa[16], pb[16];
    float s0 = 0.f, s1 = 0.f, s2 = 0.f, s3 = 0.f;
    #pragma unroll
    for (int r = 0; r < 16; r += 4) {
      pa[r]     = __builtin_amdgcn_exp2f(sa[r]);     s0 += pa[r];
      pa[r + 1] = __builtin_amdgcn_exp2f(sa[r + 1]); s1 += pa[r + 1];
      pa[r + 2] = __builtin_amdgcn_exp2f(sa[r + 2]); s2 += pa[r + 2];
      pa[r + 3] = __builtin_amdgcn_exp2f(sa[r + 3]); s3 += pa[r + 3];
    }
    #pragma unroll
    for (int r = 0; r < 16; r += 4) {
      pb[r]     = __builtin_amdgcn_exp2f(sb[r]);     s0 += pb[r];
      pb[r + 1] = __builtin_amdgcn_exp2f(sb[r + 1]); s1 += pb[r + 1];
      pb[r + 2] = __builtin_amdgcn_exp2f(sb[r + 2]); s2 += pb[r + 2];
      pb[r + 3] = __builtin_amdgcn_exp2f(sb[r + 3]); s3 += pb[r + 3];
    }
    l_run += (s0 + s1) + (s2 + s3);

    // P^T fragments DIRECT from own registers (staging permutation aligned)
    short8 pf[4];
    {
      u32x4 w0 = { cvtpk(pa[0],  pa[1]),  cvtpk(pa[2],  pa[3]),
                   cvtpk(pa[4],  pa[5]),  cvtpk(pa[6],  pa[7]) };
      u32x4 w1 = { cvtpk(pa[8],  pa[9]),  cvtpk(pa[10], pa[11]),
                   cvtpk(pa[12], pa[13]), cvtpk(pa[14], pa[15]) };
      u32x4 w2 = { cvtpk(pb[0],  pb[1]),  cvtpk(pb[2],  pb[3]),
                   cvtpk(pb[4],  pb[5]),  cvtpk(pb[6],  pb[7]) };
      u32x4 w3 = { cvtpk(pb[8],  pb[9]),  cvtpk(pb[10], pb[11]),
                   cvtpk(pb[12], pb[13]), cvtpk(pb[14], pb[15]) };
      pf[0] = __builtin_bit_cast(short8, w0);
      pf[1] = __builtin_bit_cast(short8, w1);
      pf[2] = __builtin_bit_cast(short8, w2);
      pf[3] = __builtin_bit_cast(short8, w3);
    }

    // PV: O^T += V^T @ P^T
    {
      const int rv = lane & 31;
      const int swv = (rv & 7) << 4;
      const char* Va = Vc + rv * 128;
      const char* Vb_ = Vc + (32 + rv) * 128;
      __builtin_amdgcn_s_setprio(1);
      #pragma unroll
      for (int st = 0; st < 4; ++st) {
        int inner = (st * 32 + hh * 16) ^ swv;
        short8 v0 = *reinterpret_cast<const short8*>(Va + inner);
        short8 v1 = *reinterpret_cast<const short8*>(Vb_ + inner);
        o0 = __builtin_amdgcn_mfma_f32_32x32x16_bf16(v0, pf[st], o0, 0, 0, 0);
        o1 = __builtin_amdgcn_mfma_f32_32x32x16_bf16(v1, pf[st], o1, 0, 0, 0);
      }
      __builtin_amdgcn_s_setprio(0);
    }
  };

  // main loop: steady-state counted vmcnt (never 0)
  char* Kc = Kb0; char* Kn1 = Kb1; char* Kn2 = Kb2;
  char* Vc = Vb0; char* Vn1 = Vb1; char* Vn2 = Vb2;
  for (int t = 0; t < 30; ++t) {
    stage(t + 2, Kn2, Vn2);
    tile_body(Kc, Vc);
    asm volatile("s_waitcnt vmcnt(4)" ::: "memory");   // prev tile's batch done
    __builtin_amdgcn_s_barrier();
    char* tk = Kc; Kc = Kn1; Kn1 = Kn2; Kn2 = tk;
    char* tv = Vc; Vc = Vn1; Vn1 = Vn2; Vn2 = tv;
  }
  // t = 30: last staged batch (t=31) must fully land before its reads
  tile_body(Kc, Vc);
  asm volatile("s_waitcnt vmcnt(0)" ::: "memory");
  __builtin_amdgcn_s_barrier();
  // t = 31
  tile_body(Kn1, Vn1);

  // fold in the other half-wave's kv partial sums (hoisted, once)
  l_run += __shfl_xor(l_run, 32);

  // epilogue: out[q][d] = O^T[d][q] / l ; d = (r&3) + 8*(r>>2) + 4*hh + 32*mt
  const float invl = __builtin_amdgcn_rcpf(l_run);
  const int q = qt * 128 + wid * 32 + (lane & 31);
  u16* Xp = X + (size_t)(b * 2048 + q) * 768;
  #pragma unroll
  for (int mt = 0; mt < 2; ++mt) {
    #pragma unroll
    for (int rr = 0; rr < 4; ++rr) {
      float e0 = (mt ? o1[rr * 4 + 0] : o0[rr * 4 + 0]) * invl;
      float e1 = (mt ? o1[rr * 4 + 1] : o0[rr * 4 + 1]) * invl;
      float e2 = (mt ? o1[rr * 4 + 2] : o0[rr * 4 + 2]) * invl;
      float e3 = (mt ? o1[rr * 4 + 3] : o0[rr * 4 + 3]) * invl;
      int col = h * 64 + mt * 32 + 8 * rr + 4 * hh;
      u64 pk = (u64)f2bf(e0) | ((u64)f2bf(e1) << 16)
             | ((u64)f2bf(e2) << 32) | ((u64)f2bf(e3) << 48);
      *reinterpret_cast<u64*>(Xp + col) = pk;
    }
  }
}

// ---- launch --------------------------------------------------------------

extern "C" void kernel_launch(void* const* d_in, const int* in_sizes, int n_in,
                              void* d_out, int out_size, void* d_ws, size_t ws_size,
                              hipStream_t stream) {
  const float* query = (const float*)d_in[0];
  const float* key   = (const float*)d_in[1];
  const float* value = (const float*)d_in[2];
  const float* Wq    = (const float*)d_in[3];
  const float* Wk    = (const float*)d_in[4];
  const float* Wv    = (const float*)d_in[5];
  const float* Wo    = (const float*)d_in[6];
  const float* bo    = (const float*)d_in[7];

  char* ws = (char*)d_ws;
  u16* Wcat = (u16*)ws;                                // [2304][768]
  u16* WoB  = (u16*)(ws + (size_t)2304 * 768 * 2);     // [768][768]
  u16* Xq   = (u16*)(ws + (size_t)2304 * 768 * 2 + (size_t)768 * 768 * 2);
  u16* Xk   = Xq  + (size_t)8192 * 768;
  u16* Xv   = Xk  + (size_t)8192 * 768;
  u16* QKb  = Xv  + (size_t)8192 * 768;                // [8192][1536] Q|K
  u16* VtB  = QKb + (size_t)8192 * 1536;               // [48][64][2048] V^T

  const float qs = 0.125f * 1.4426950408889634f;       // Dh^-0.5 * log2(e)
  cvtw_kernel<<<dim3(576, 4), 256, 0, stream>>>(Wq, Wk, Wv, Wo, Wcat, WoB, 147456, qs);
  cvt3_kernel<<<dim3(6144, 3), 256, 0, stream>>>(query, key, value, Xq, Xk, Xv, 1572864);

  gemm128<0><<<dim3(1152), 256, 0, stream>>>(Xq, Xk, Xv, Wcat, QKb, VtB, nullptr, nullptr);
  attn_fwd<<<dim3(768), 256, 0, stream>>>(QKb, VtB, Xq);   // Xq reused as attn out
  gemm128<1><<<dim3(384), 256, 0, stream>>>(Xq, nullptr, nullptr, WoB, nullptr, nullptr,
                                            (float*)d_out, bo);
}

// Round 11
// 161.345 us; speedup vs baseline: 1.0638x; 1.0638x over previous
//
#include <hip/hip_runtime.h>
#include <hip/hip_bf16.h>
#include <stdint.h>

typedef unsigned short u16;
typedef unsigned int   u32;
typedef unsigned long long u64;

typedef __attribute__((ext_vector_type(8)))  short short8;   // 8 bf16 (4 VGPR)
typedef __attribute__((ext_vector_type(4)))  u32   u32x4;
typedef __attribute__((ext_vector_type(4)))  float f32x4;
typedef __attribute__((ext_vector_type(16))) float f32x16;

// ---- helpers -------------------------------------------------------------

__device__ __forceinline__ u16 f2bf(float f) {           // RNE f32 -> bf16 bits
  u32 u = __builtin_bit_cast(u32, f);
  u += 0x7FFFu + ((u >> 16) & 1u);
  return (u16)(u >> 16);
}

__device__ __forceinline__ void gload16(const void* g, void* l) {
  __builtin_amdgcn_global_load_lds((__attribute__((address_space(1))) void*)(g),
                                   (__attribute__((address_space(3))) void*)(l),
                                   16, 0, 0);
}

__device__ __forceinline__ u32 cvtpk(float lo, float hi) {
  u32 r;
  asm("v_cvt_pk_bf16_f32 %0, %1, %2" : "=v"(r) : "v"(lo), "v"(hi));
  return r;
}

// ---- weight f32 -> bf16 convert ------------------------------------------

__global__ __launch_bounds__(256)
void cvtw_kernel(const float* __restrict__ Wq, const float* __restrict__ Wk,
                 const float* __restrict__ Wv, const float* __restrict__ Wo,
                 u16* __restrict__ Wcat, u16* __restrict__ WoB, int n4, float qs) {
  int i = blockIdx.x * 256 + threadIdx.x;
  if (i >= n4) return;
  int y = blockIdx.y;
  const float* in = y == 0 ? Wq : y == 1 ? Wk : y == 2 ? Wv : Wo;
  u16* out = y == 0 ? Wcat : y == 1 ? (Wcat + 589824) : y == 2 ? (Wcat + 1179648) : WoB;
  float s = y == 0 ? qs : 1.f;
  float4 v = reinterpret_cast<const float4*>(in)[i];
  u64 pk = (u64)f2bf(v.x * s) | ((u64)f2bf(v.y * s) << 16)
         | ((u64)f2bf(v.z * s) << 32) | ((u64)f2bf(v.w * s) << 48);
  reinterpret_cast<u64*>(out)[i] = pk;
}

// ---- 128x128 tile GEMM, C = A @ B^T (nn.Linear), bf16 MFMA ---------------
// MODE 0: A is f32 (query/key/value per bn), staged via global_load_lds into
//   an XOR-swizzled f32 LDS tile (pre-swizzled source; conflict-free reads),
//   converted to bf16 with cvt_pk at fragment-read time. Kills the cvt3 pass.
// MODE 1: A is bf16 (attn output); f32 out + bias.
// 1D grid + bijective XCD swizzle, decoded bn-fastest (A panel L2-resident).
template<int MODE>
__global__ __launch_bounds__(256)
void gemm128(const float* __restrict__ Af0, const float* __restrict__ Af1,
             const float* __restrict__ Af2, const u16* __restrict__ Ab,
             const u16* __restrict__ Bw,
             u16* __restrict__ Cqk, u16* __restrict__ Vt,
             float* __restrict__ Cout, const float* __restrict__ bias) {
  constexpr int K  = 768;
  constexpr int KT = K / 32;
  constexpr int NBN = (MODE == 0) ? 18 : 6;
  __shared__ char lds[(MODE == 0) ? 49152 : 32768];
  char* A0 = lds;
  char* A1 = lds + ((MODE == 0) ? 16384 : 8192);
  char* B0 = lds + ((MODE == 0) ? 32768 : 16384);
  char* B1 = B0 + 8192;

  const int tid = threadIdx.x, lane = tid & 63, wid = tid >> 6;
  const int hw = blockIdx.x;
  const int L = (hw & 7) * (64 * NBN / 8) + (hw >> 3);
  const int bm = L / NBN, bn = L - bm * NBN;
  const int wr = wid >> 1, wc = wid & 1;

  const char* Agf = nullptr;   // MODE 0: f32 A panel
  const char* Ag16 = nullptr;  // MODE 1: bf16 A panel
  if constexpr (MODE == 0) {
    const float* Asrc = (bn < 6) ? Af0 : (bn < 12) ? Af1 : Af2;
    Agf = (const char*)(Asrc + (size_t)bm * 128 * 768);
  } else {
    Ag16 = (const char*)Ab + (size_t)bm * 128 * (K * 2);
  }
  const char* Bg = (const char*)Bw + (size_t)bn * 128 * (K * 2);

  f32x4 acc[4][4];
  #pragma unroll
  for (int m = 0; m < 4; ++m)
    #pragma unroll
    for (int n = 0; n < 4; ++n)
      #pragma unroll
      for (int r = 0; r < 4; ++r) acc[m][n][r] = 0.f;

  // A staging, MODE 0: f32 tile 128 rows x 128B, source pre-swizzled so LDS
  // is linear and reads use (offset ^ (row&7)<<4) -> conflict-free.
  auto stageA32 = [&](char* An, int kt) {
    if constexpr (MODE == 0) {
      #pragma unroll
      for (int j = 0; j < 4; ++j) {
        int off = j * 4096 + wid * 1024 + lane * 16;
        int row = off >> 7;
        int isl = (off & 127) ^ ((row & 7) << 4);
        gload16(Agf + (size_t)row * 3072 + kt * 128 + isl, An + off);
      }
    }
  };
  auto stageA16 = [&](char* An, int kt) {
    if constexpr (MODE == 1) {
      #pragma unroll
      for (int c = 0; c < 2; ++c) {
        int off = (c * 4 + wid) * 1024 + lane * 16;
        int row = off >> 6, colb = off & 63;
        gload16(Ag16 + (size_t)row * (K * 2) + kt * 64 + colb, An + off);
      }
    }
  };
  auto stageB = [&](char* Bn, int kt) {
    #pragma unroll
    for (int c = 0; c < 2; ++c) {
      int off = (c * 4 + wid) * 1024 + lane * 16;
      int row = off >> 6, colb = off & 63;
      gload16(Bg + (size_t)row * (K * 2) + kt * 64 + colb, Bn + off);
    }
  };

  // prologue: kt = 0
  stageA32(A0, 0);
  stageA16(A0, 0);
  stageB(B0, 0);
  __syncthreads();

  for (int kt = 0; kt < KT; ++kt) {
    const int cur = kt & 1;
    char* Ac = cur ? A1 : A0;  char* Bc = cur ? B1 : B0;
    char* An = cur ? A0 : A1;  char* Bn = cur ? B0 : B1;
    if (kt + 1 < KT) {
      stageA32(An, kt + 1);
      stageA16(An, kt + 1);
      stageB(Bn, kt + 1);
    }
    short8 af[4], bf[4];
    #pragma unroll
    for (int m = 0; m < 4; ++m) {
      int row = wr * 64 + m * 16 + (lane & 15);
      if constexpr (MODE == 0) {
        int swz = (row & 7) << 4;
        int o1 = (lane >> 4) * 32;
        const char* Ar = Ac + row * 128;
        f32x4 lo = *reinterpret_cast<const f32x4*>(Ar + (o1 ^ swz));
        f32x4 hi = *reinterpret_cast<const f32x4*>(Ar + ((o1 + 16) ^ swz));
        u32x4 pk = { cvtpk(lo[0], lo[1]), cvtpk(lo[2], lo[3]),
                     cvtpk(hi[0], hi[1]), cvtpk(hi[2], hi[3]) };
        af[m] = __builtin_bit_cast(short8, pk);
      } else {
        af[m] = *reinterpret_cast<const short8*>(Ac + row * 64 + ((lane >> 4) * 16));
      }
    }
    #pragma unroll
    for (int n = 0; n < 4; ++n) {
      int row = wc * 64 + n * 16 + (lane & 15);
      bf[n] = *reinterpret_cast<const short8*>(Bc + row * 64 + ((lane >> 4) * 16));
    }
    #pragma unroll
    for (int m = 0; m < 4; ++m)
      #pragma unroll
      for (int n = 0; n < 4; ++n)
        acc[m][n] = __builtin_amdgcn_mfma_f32_16x16x32_bf16(af[m], bf[n], acc[m][n], 0, 0, 0);
    __syncthreads();
  }

  if constexpr (MODE == 0) {
    if (bn < 12) {
      #pragma unroll
      for (int m = 0; m < 4; ++m) {
        int grow0 = bm * 128 + wr * 64 + m * 16 + ((lane >> 4) << 2);
        #pragma unroll
        for (int n = 0; n < 4; ++n) {
          int col = bn * 128 + wc * 64 + n * 16 + (lane & 15);
          #pragma unroll
          for (int r = 0; r < 4; ++r)
            Cqk[(size_t)(grow0 + r) * 1536 + col] = f2bf(acc[m][n][r]);
        }
      }
    } else {
      #pragma unroll
      for (int m = 0; m < 4; ++m) {
        int grow0 = bm * 128 + wr * 64 + m * 16 + ((lane >> 4) << 2);
        int bb = grow0 >> 11, nn = grow0 & 2047;
        #pragma unroll
        for (int n = 0; n < 4; ++n) {
          int vc = (bn - 12) * 128 + wc * 64 + n * 16 + (lane & 15);
          int hid = vc >> 6, d = vc & 63;
          u64 pk = (u64)f2bf(acc[m][n][0]) | ((u64)f2bf(acc[m][n][1]) << 16)
                 | ((u64)f2bf(acc[m][n][2]) << 32) | ((u64)f2bf(acc[m][n][3]) << 48);
          *reinterpret_cast<u64*>(Vt + ((size_t)(bb * 12 + hid) * 64 + d) * 2048 + nn) = pk;
        }
      }
    }
  } else {
    #pragma unroll
    for (int m = 0; m < 4; ++m) {
      int grow0 = bm * 128 + wr * 64 + m * 16 + ((lane >> 4) << 2);
      #pragma unroll
      for (int n = 0; n < 4; ++n) {
        int col = bn * 128 + wc * 64 + n * 16 + (lane & 15);
        float bs = bias[col];
        #pragma unroll
        for (int r = 0; r < 4; ++r)
          Cout[(size_t)(grow0 + r) * 768 + col] = acc[m][n][r] + bs;
      }
    }
  }
}

// ---- flash attention, swapped-operand 32x32 MFMA (R9-passing, reverted) --
__global__ __launch_bounds__(256)
void attn_fwd(const u16* __restrict__ QK, const u16* __restrict__ Vt,
              u16* __restrict__ X) {
  __shared__ char lds[32768];
  char* K0 = lds;          char* K1 = lds + 8192;
  char* V0 = lds + 16384;  char* V1 = lds + 24576;

  const int tid = threadIdx.x, lane = tid & 63, wid = tid >> 6;
  const int hw = blockIdx.x;
  const int L = (hw & 7) * 96 + (hw >> 3);
  const int bh = L >> 4, qt = L & 15;
  const int b = bh / 12, h = bh - b * 12;
  const int hh = lane >> 5;

  const char* Qg = (const char*)QK + ((size_t)(b * 2048 + qt * 128) * 1536 + h * 64) * 2;
  const char* Kg = (const char*)QK + ((size_t)(b * 2048) * 1536 + 768 + h * 64) * 2;
  const char* Vg = (const char*)Vt + ((size_t)bh * 64 * 2048) * 2;

  const int off0 = wid * 1024 + lane * 16;
  const int off1 = off0 + 4096;
  const int r0 = off0 >> 7, i0 = (off0 & 127) ^ ((r0 & 7) << 4);
  const int r1 = off1 >> 7, i1 = (off1 & 127) ^ ((r1 & 7) << 4);
  const int pb0 = (r0 >> 2) & 7, pb1 = (r1 >> 2) & 7;
  const int kr0 = (r0 & 32) | ((((pb0 & 1) << 1) | ((pb0 >> 1) & 1) | (pb0 & 4)) << 2) | (r0 & 3);
  const int kr1 = (r1 & 32) | ((((pb1 & 1) << 1) | ((pb1 >> 1) & 1) | (pb1 & 4)) << 2) | (r1 & 3);
  const size_t kso0 = (size_t)kr0 * 3072 + i0, kso1 = (size_t)kr1 * 3072 + i1;
  const size_t vso0 = (size_t)r0 * 4096 + i0, vso1 = (size_t)r1 * 4096 + i1;

  gload16(Kg + kso0, K0 + off0);
  gload16(Kg + kso1, K0 + off1);
  gload16(Vg + vso0, V0 + off0);
  gload16(Vg + vso1, V0 + off1);

  short8 qf[4];
  {
    const char* Qrow = Qg + (size_t)(wid * 32 + (lane & 31)) * 3072 + hh * 16;
    #pragma unroll
    for (int kk = 0; kk < 4; ++kk)
      qf[kk] = *reinterpret_cast<const short8*>(Qrow + kk * 32);
  }
  __syncthreads();

  f32x16 o0, o1;
  #pragma unroll
  for (int r = 0; r < 16; ++r) { o0[r] = 0.f; o1[r] = 0.f; }
  float l_run = 0.f;

  for (int t = 0; t < 32; ++t) {
    const int cur = t & 1;
    char* Kc = cur ? K1 : K0;  char* Vc = cur ? V1 : V0;
    char* Kn = cur ? K0 : K1;  char* Vn = cur ? V0 : V1;
    if (t + 1 < 32) {
      const char* Kgn = Kg + (size_t)(t + 1) * 64 * 3072;
      const char* Vgn = Vg + (size_t)(t + 1) * 128;
      gload16(Kgn + kso0, Kn + off0);
      gload16(Kgn + kso1, Kn + off1);
      gload16(Vgn + vso0, Vn + off0);
      gload16(Vgn + vso1, Vn + off1);
    }

    f32x16 sa, sb;
    #pragma unroll
    for (int r = 0; r < 16; ++r) { sa[r] = 0.f; sb[r] = 0.f; }
    {
      const int ra = lane & 31;
      const int swa = (ra & 7) << 4;
      const char* Ka = Kc + ra * 128;
      const char* Kb2 = Kc + (32 + ra) * 128;
      __builtin_amdgcn_s_setprio(1);
      #pragma unroll
      for (int kk = 0; kk < 4; ++kk) {
        int inner = (kk * 32 + hh * 16) ^ swa;
        short8 ka = *reinterpret_cast<const short8*>(Ka + inner);
        short8 kb = *reinterpret_cast<const short8*>(Kb2 + inner);
        sa = __builtin_amdgcn_mfma_f32_32x32x16_bf16(ka, qf[kk], sa, 0, 0, 0);
        sb = __builtin_amdgcn_mfma_f32_32x32x16_bf16(kb, qf[kk], sb, 0, 0, 0);
      }
      __builtin_amdgcn_s_setprio(0);
    }

    float pa[16], pb[16];
    float s0 = 0.f, s1 = 0.f, s2 = 0.f, s3 = 0.f;
    #pragma unroll
    for (int r = 0; r < 16; r += 4) {
      pa[r]     = __builtin_amdgcn_exp2f(sa[r]);     s0 += pa[r];
      pa[r + 1] = __builtin_amdgcn_exp2f(sa[r + 1]); s1 += pa[r + 1];
      pa[r + 2] = __builtin_amdgcn_exp2f(sa[r + 2]); s2 += pa[r + 2];
      pa[r + 3] = __builtin_amdgcn_exp2f(sa[r + 3]); s3 += pa[r + 3];
    }
    #pragma unroll
    for (int r = 0; r < 16; r += 4) {
      pb[r]     = __builtin_amdgcn_exp2f(sb[r]);     s0 += pb[r];
      pb[r + 1] = __builtin_amdgcn_exp2f(sb[r + 1]); s1 += pb[r + 1];
      pb[r + 2] = __builtin_amdgcn_exp2f(sb[r + 2]); s2 += pb[r + 2];
      pb[r + 3] = __builtin_amdgcn_exp2f(sb[r + 3]); s3 += pb[r + 3];
    }
    l_run += (s0 + s1) + (s2 + s3);

    short8 pf[4];
    {
      u32x4 w0 = { cvtpk(pa[0],  pa[1]),  cvtpk(pa[2],  pa[3]),
                   cvtpk(pa[4],  pa[5]),  cvtpk(pa[6],  pa[7]) };
      u32x4 w1 = { cvtpk(pa[8],  pa[9]),  cvtpk(pa[10], pa[11]),
                   cvtpk(pa[12], pa[13]), cvtpk(pa[14], pa[15]) };
      u32x4 w2 = { cvtpk(pb[0],  pb[1]),  cvtpk(pb[2],  pb[3]),
                   cvtpk(pb[4],  pb[5]),  cvtpk(pb[6],  pb[7]) };
      u32x4 w3 = { cvtpk(pb[8],  pb[9]),  cvtpk(pb[10], pb[11]),
                   cvtpk(pb[12], pb[13]), cvtpk(pb[14], pb[15]) };
      pf[0] = __builtin_bit_cast(short8, w0);
      pf[1] = __builtin_bit_cast(short8, w1);
      pf[2] = __builtin_bit_cast(short8, w2);
      pf[3] = __builtin_bit_cast(short8, w3);
    }

    {
      const int rv = lane & 31;
      const int swv = (rv & 7) << 4;
      const char* Va = Vc + rv * 128;
      const char* Vb = Vc + (32 + rv) * 128;
      __builtin_amdgcn_s_setprio(1);
      #pragma unroll
      for (int st = 0; st < 4; ++st) {
        int inner = (st * 32 + hh * 16) ^ swv;
        short8 v0 = *reinterpret_cast<const short8*>(Va + inner);
        short8 v1 = *reinterpret_cast<const short8*>(Vb + inner);
        o0 = __builtin_amdgcn_mfma_f32_32x32x16_bf16(v0, pf[st], o0, 0, 0, 0);
        o1 = __builtin_amdgcn_mfma_f32_32x32x16_bf16(v1, pf[st], o1, 0, 0, 0);
      }
      __builtin_amdgcn_s_setprio(0);
    }
    __syncthreads();
  }

  l_run += __shfl_xor(l_run, 32);

  const float invl = __builtin_amdgcn_rcpf(l_run);
  const int q = qt * 128 + wid * 32 + (lane & 31);
  u16* Xp = X + (size_t)(b * 2048 + q) * 768;
  #pragma unroll
  for (int mt = 0; mt < 2; ++mt) {
    #pragma unroll
    for (int rr = 0; rr < 4; ++rr) {
      float e0 = (mt ? o1[rr * 4 + 0] : o0[rr * 4 + 0]) * invl;
      float e1 = (mt ? o1[rr * 4 + 1] : o0[rr * 4 + 1]) * invl;
      float e2 = (mt ? o1[rr * 4 + 2] : o0[rr * 4 + 2]) * invl;
      float e3 = (mt ? o1[rr * 4 + 3] : o0[rr * 4 + 3]) * invl;
      int col = h * 64 + mt * 32 + 8 * rr + 4 * hh;
      u64 pk = (u64)f2bf(e0) | ((u64)f2bf(e1) << 16)
             | ((u64)f2bf(e2) << 32) | ((u64)f2bf(e3) << 48);
      *reinterpret_cast<u64*>(Xp + col) = pk;
    }
  }
}

// ---- launch --------------------------------------------------------------

extern "C" void kernel_launch(void* const* d_in, const int* in_sizes, int n_in,
                              void* d_out, int out_size, void* d_ws, size_t ws_size,
                              hipStream_t stream) {
  const float* query = (const float*)d_in[0];
  const float* key   = (const float*)d_in[1];
  const float* value = (const float*)d_in[2];
  const float* Wq    = (const float*)d_in[3];
  const float* Wk    = (const float*)d_in[4];
  const float* Wv    = (const float*)d_in[5];
  const float* Wo    = (const float*)d_in[6];
  const float* bo    = (const float*)d_in[7];

  char* ws = (char*)d_ws;
  u16* Wcat = (u16*)ws;                                // [2304][768]
  u16* WoB  = (u16*)(ws + (size_t)2304 * 768 * 2);     // [768][768]
  u16* Xq   = (u16*)(ws + (size_t)2304 * 768 * 2 + (size_t)768 * 768 * 2);
  u16* QKb  = Xq  + (size_t)8192 * 768;                // [8192][1536] Q|K
  u16* VtB  = QKb + (size_t)8192 * 1536;               // [48][64][2048] V^T

  const float qs = 0.125f * 1.4426950408889634f;       // Dh^-0.5 * log2(e)
  cvtw_kernel<<<dim3(576, 4), 256, 0, stream>>>(Wq, Wk, Wv, Wo, Wcat, WoB, 147456, qs);

  gemm128<0><<<dim3(1152), 256, 0, stream>>>(query, key, value, nullptr, Wcat,
                                             QKb, VtB, nullptr, nullptr);
  attn_fwd<<<dim3(768), 256, 0, stream>>>(QKb, VtB, Xq);   // Xq = attn out (bf16)
  gemm128<1><<<dim3(384), 256, 0, stream>>>(nullptr, nullptr, nullptr, Xq, WoB,
                                            nullptr, nullptr, (float*)d_out, bo);
}